// Round 5
// baseline (212.406 us; speedup 1.0000x reference)
//
#include <hip/hip_runtime.h>

#define NB   16
#define NSQ  1024
#define NSKV 1024
#define ND   256

typedef __bf16    bf16x8 __attribute__((ext_vector_type(8)));
typedef float     f32x4  __attribute__((ext_vector_type(4)));

// ---- merged prep: cvt K->bf16 in MFMA-FRAGMENT ORDER | pack mask bits | zero colsum | zero out0
// Kbf layout: bf16x8 index i = (((b*64 + kvblk)*8 + dc)*64 + kg*16 + m)
// holding K[b][kvblk*16 + m][dc*32 + kg*8 .. +8].
__global__ __launch_bounds__(256) void prep_kernel(
    const float* __restrict__ K, __bf16* __restrict__ Kbf,
    const int* __restrict__ mask, unsigned* __restrict__ mw,
    float* __restrict__ colsum, float* __restrict__ out0)
{
    const int bid = blockIdx.x;
    const int tid = threadIdx.x;
    if (bid < 2048) {
        const int i    = bid * 256 + tid;
        const int lane = i & 63;
        const int m    = lane & 15;
        const int kg   = lane >> 4;
        const int dc   = (i >> 6) & 7;
        const int kvb  = (i >> 9) & 63;
        const int b    = i >> 15;
        const float* s = K + ((size_t)(b * NSKV + kvb * 16 + m)) * ND + dc * 32 + kg * 8;
        float4 a = *(const float4*)s;
        float4 c = *(const float4*)(s + 4);
        bf16x8 o;
        o[0] = (__bf16)a.x; o[1] = (__bf16)a.y; o[2] = (__bf16)a.z; o[3] = (__bf16)a.w;
        o[4] = (__bf16)c.x; o[5] = (__bf16)c.y; o[6] = (__bf16)c.z; o[7] = (__bf16)c.w;
        ((bf16x8*)Kbf)[i] = o;
    } else if (bid < 2048 + 4096) {
        // mask -> bits: mw[row*64 + hp*16 + m], bit c = mask[row][hp*256+c*16+m]!=0
        const int row = (bid - 2048) * 4 + (tid >> 6);
        const int l   = tid & 63;
        const int4* mrow = (const int4*)(mask + (size_t)row * NSKV) + l * 4;
        unsigned w = 0;
        #pragma unroll
        for (int v = 0; v < 4; ++v) {
            int4 mv = mrow[v];
            w |= (mv.x != 0 ? 1u : 0u) << (v * 4 + 0);
            w |= (mv.y != 0 ? 1u : 0u) << (v * 4 + 1);
            w |= (mv.z != 0 ? 1u : 0u) << (v * 4 + 2);
            w |= (mv.w != 0 ? 1u : 0u) << (v * 4 + 3);
        }
        const int m    = l & 15;
        const int base = l & 48;
        unsigned out = 0;
        #pragma unroll
        for (int c = 0; c < 16; ++c) {
            unsigned v = (unsigned)__shfl((int)w, base | c);
            out |= ((v >> m) & 1u) << c;
        }
        mw[(size_t)row * 64 + l] = out;
    } else if (bid < 2048 + 4096 + 64) {
        colsum[(bid - 6144) * 256 + tid] = 0.f;
    } else {
        out0[(bid - 6208) * 256 + tid] = 0.f;
    }
}

__device__ __forceinline__ void gload_lds16(const void* g, void* l) {
    __builtin_amdgcn_global_load_lds(
        (const __attribute__((address_space(1))) void*)g,
        (__attribute__((address_space(3))) void*)l, 16, 0, 0);
}

// Shared structure of zk/pk:
//   grid 256 x 256 thr (4 waves).  Block = 64 q-rows (wave h = rows q0+h*16)
//   x FULL kv.  All 4 waves share each staged 64-kv-row chunk (32 KB bf16,
//   fragment-ordered, contiguous in Kbf) -> per-CU global-load slots drop
//   2048 -> 512 vs the old 16-row blocks.  Staging = global_load_lds
//   (no VGPR round-trip to collapse), double-buffered, raw s_barrier +
//   counted vmcnt (NOT __syncthreads: it would drain in-flight stores).
//   XCD swizzle: tile=((g&7)<<5)|(g>>3) -> each XCD owns 2 batches; Kbf
//   slice 1 MB -> L2-resident.
//   Mask: u64 per q-row, bit C = sub-chunk C (runtime-shift, no scratch).

#define PROLOGUE_COMMON \
    const int g    = blockIdx.x; \
    const int tile = ((g & 7) << 5) | (g >> 3); \
    const int b    = tile >> 4; \
    const int q0   = (tile & 15) * 64; \
    const int tid  = threadIdx.x; \
    const int lane = tid & 63; \
    const int h    = tid >> 6; \
    const int m    = lane & 15; \
    const int kg   = lane >> 4; \
    const int r0   = q0 + h * 16; \
    bf16x8 afrag[8]; \
    { \
        const float* qbase = Q + ((size_t)(b * NSQ + r0 + m)) * ND; \
        _Pragma("unroll") \
        for (int dc = 0; dc < 8; ++dc) { \
            const float* p4 = qbase + dc * 32 + kg * 8; \
            float4 x = *(const float4*)(p4); \
            float4 y = *(const float4*)(p4 + 4); \
            bf16x8 a; \
            a[0] = (__bf16)x.x; a[1] = (__bf16)x.y; a[2] = (__bf16)x.z; a[3] = (__bf16)x.w; \
            a[4] = (__bf16)y.x; a[5] = (__bf16)y.y; a[6] = (__bf16)y.z; a[7] = (__bf16)y.w; \
            afrag[dc] = a; \
        } \
    } \
    unsigned long long mbits[4]; \
    _Pragma("unroll") \
    for (int i = 0; i < 4; ++i) { \
        const unsigned* wp = mw + (size_t)(b * NSQ + r0 + kg * 4 + i) * 64 + m; \
        unsigned long long w0 = wp[0], w1 = wp[16], w2 = wp[32], w3 = wp[48]; \
        mbits[i] = w0 | (w1 << 16) | (w2 << 32) | (w3 << 48); \
    } \
    const char* ksrc = (const char*)Kbf + (size_t)b * 64 * 512 * 16; \
    const int soff = h * 8192 + lane * 16; \
    const int doff = h * 8192;

#define DMA(c, dst) { \
    const char* _g = ksrc + (size_t)(c) * 32768 + soff; \
    char* _l = (dst) + doff; \
    _Pragma("unroll") \
    for (int j = 0; j < 8; ++j) \
        gload_lds16(_g + j * 1024, _l + j * 1024); }

#define SYNC(N) { asm volatile("s_waitcnt vmcnt(" #N ")" ::: "memory"); \
                  __builtin_amdgcn_s_barrier(); \
                  __builtin_amdgcn_sched_barrier(0); }

// ---- pass A: Z only -> invZ[b,q] ----
__global__ __launch_bounds__(256) void zk_kernel(
    const float* __restrict__ Q, const __bf16* __restrict__ Kbf,
    const unsigned* __restrict__ mw, float* __restrict__ invZ)
{
    __shared__ __attribute__((aligned(16))) char kst[2][32768];
    PROLOGUE_COMMON
    char* b0 = &kst[0][0];
    char* b1 = &kst[1][0];
    float zacc[4] = {0.f, 0.f, 0.f, 0.f};

    #define ZCOMP(cb, c) { \
        _Pragma("unroll") \
        for (int cs = 0; cs < 4; ++cs) { \
            f32x4 acc = {0.f, 0.f, 0.f, 0.f}; \
            _Pragma("unroll") \
            for (int dc = 0; dc < 8; ++dc) { \
                bf16x8 bfr = *(const bf16x8*)((cb) + cs * 8192 + dc * 1024 + lane * 16); \
                acc = __builtin_amdgcn_mfma_f32_16x16x32_bf16(afrag[dc], bfr, acc, 0, 0, 0); \
            } \
            const int C_ = (c) * 4 + cs; \
            _Pragma("unroll") \
            for (int i = 0; i < 4; ++i) { \
                float e = ((mbits[i] >> C_) & 1ull) ? __expf(__expf(acc[i]) * 0.0625f) : 0.f; \
                zacc[i] += e; \
            } \
        } }

    DMA(0, b0);
    SYNC(0);
    DMA(1, b1);
    for (int c = 0; c < 16; c += 2) {
        ZCOMP(b0, c);
        SYNC(0);
        if (c + 2 < 16) DMA(c + 2, b0);
        ZCOMP(b1, c + 1);
        if (c + 2 < 16) {
            SYNC(0);
            DMA(c + 3, b1);
        }
    }
    #undef ZCOMP

    #pragma unroll
    for (int i = 0; i < 4; ++i) {
        float z = zacc[i];
        z += __shfl_xor(z, 1);
        z += __shfl_xor(z, 2);
        z += __shfl_xor(z, 4);
        z += __shfl_xor(z, 8);
        if (m == 0) invZ[b * NSQ + r0 + kg * 4 + i] = 1.0f / z;
    }
}

// ---- pass B: p = e * invZ streamed out per chunk; colsum folded in ----
// VMEM per chunk-compute = 4 sub-chunks x (4 stores + 1 atomic) = 20
// -> SYNC(20) leaves exactly those in flight while draining the next DMA.
__global__ __launch_bounds__(256) void pk_kernel(
    const float* __restrict__ Q, const __bf16* __restrict__ Kbf,
    const unsigned* __restrict__ mw, const float* __restrict__ invZ,
    float* __restrict__ out_p, float* __restrict__ colsum)
{
    __shared__ __attribute__((aligned(16))) char kst[2][32768];
    PROLOGUE_COMMON
    char* b0 = &kst[0][0];
    char* b1 = &kst[1][0];

    float iz[4];
    #pragma unroll
    for (int i = 0; i < 4; ++i)
        iz[i] = invZ[b * NSQ + r0 + kg * 4 + i];

    float* pr0 = out_p + (size_t)(b * NSQ + r0 + kg * 4) * NSKV + m;
    float* csb = colsum + b * NSKV + m;

    #define PCOMP(cb, c) { \
        _Pragma("unroll") \
        for (int cs = 0; cs < 4; ++cs) { \
            f32x4 acc = {0.f, 0.f, 0.f, 0.f}; \
            _Pragma("unroll") \
            for (int dc = 0; dc < 8; ++dc) { \
                bf16x8 bfr = *(const bf16x8*)((cb) + cs * 8192 + dc * 1024 + lane * 16); \
                acc = __builtin_amdgcn_mfma_f32_16x16x32_bf16(afrag[dc], bfr, acc, 0, 0, 0); \
            } \
            const int C_ = (c) * 4 + cs; \
            float cssum = 0.f; \
            _Pragma("unroll") \
            for (int i = 0; i < 4; ++i) { \
                float e  = ((mbits[i] >> C_) & 1ull) ? __expf(__expf(acc[i]) * 0.0625f) : 0.f; \
                float pv = e * iz[i]; \
                pr0[(size_t)i * NSKV + C_ * 16] = pv; \
                cssum += pv; \
            } \
            cssum += __shfl_xor(cssum, 16); \
            cssum += __shfl_xor(cssum, 32); \
            if (kg == 0) atomicAdd(csb + C_ * 16, cssum); \
        } }

    DMA(0, b0);
    SYNC(0);
    DMA(1, b1);
    for (int c = 0; c < 16; c += 2) {
        PCOMP(b0, c);
        SYNC(20);
        if (c + 2 < 16) DMA(c + 2, b0);
        PCOMP(b1, c + 1);
        if (c + 2 < 16) {
            SYNC(20);
            DMA(c + 3, b1);
        }
    }
    #undef PCOMP
}

// out[b,d] = sum_k colsum[b,k] * V[b,k,d]; 1024 blocks, 16 k-rows each.
__global__ __launch_bounds__(256) void attn_out_kernel(
    const float* __restrict__ colsum, const float* __restrict__ V,
    float* __restrict__ out)
{
    const int b  = blockIdx.x >> 6;
    const int ks = (blockIdx.x & 63) << 4;
    const int d  = threadIdx.x;
    float acc = 0.f;
    #pragma unroll
    for (int k = 0; k < 16; ++k) {
        acc += colsum[b * NSKV + ks + k] * V[((size_t)(b * NSKV + ks + k)) * ND + d];
    }
    atomicAdd(&out[b * ND + d], acc);
}

extern "C" void kernel_launch(void* const* d_in, const int* in_sizes, int n_in,
                              void* d_out, int out_size, void* d_ws, size_t ws_size,
                              hipStream_t stream)
{
    (void)in_sizes; (void)n_in; (void)out_size; (void)ws_size;
    const float* Q    = (const float*)d_in[0];
    const float* K    = (const float*)d_in[1];
    const float* V    = (const float*)d_in[2];
    const int*   mask = (const int*)d_in[3];

    float* out0 = (float*)d_out;            // (B, D) = 4096 floats
    float* p    = out0 + NB * ND;           // p_attn (B, SQ, SKV)

    float*    colsum = (float*)d_ws;                                    // 64 KB
    float*    invZ   = (float*)((char*)d_ws + (64 << 10));              // 64 KB
    __bf16*   Kbf    = (__bf16*)((char*)d_ws + (128 << 10));            // 8.39 MB
    unsigned* mwbits = (unsigned*)((char*)d_ws + (128 << 10) + (size_t)NB * NSKV * ND * 2); // 4.19 MB

    prep_kernel<<<6224, 256, 0, stream>>>(K, Kbf, mask, mwbits, colsum, out0);
    zk_kernel<<<256, 256, 0, stream>>>(Q, Kbf, mwbits, invZ);
    pk_kernel<<<256, 256, 0, stream>>>(Q, Kbf, mwbits, invZ, p, colsum);
    attn_out_kernel<<<NB * 64, 256, 0, stream>>>(colsum, V, out0);
}

// Round 6
// 198.982 us; speedup vs baseline: 1.0675x; 1.0675x over previous
//
#include <hip/hip_runtime.h>

#define NB   16
#define NSQ  1024
#define NSKV 1024
#define ND   256

typedef __bf16    bf16x8 __attribute__((ext_vector_type(8)));
typedef float     f32x4  __attribute__((ext_vector_type(4)));
typedef _Float16  f16x4  __attribute__((ext_vector_type(4)));

#define EST 268   // e-park LDS row stride in f16 elems (536 B): kg groups on disjoint banks

// ---- merged prep: cvt K->bf16 in MFMA-FRAGMENT ORDER | pack mask bits | zero colsum | zero out0
// Kbf layout: bf16x8 index i = (((b*64 + kvblk)*8 + dc)*64 + kg*16 + m)
// holding K[b][kvblk*16 + m][dc*32 + kg*8 .. +8].
__global__ __launch_bounds__(256) void prep_kernel(
    const float* __restrict__ K, __bf16* __restrict__ Kbf,
    const int* __restrict__ mask, unsigned* __restrict__ mw,
    float* __restrict__ colsum, float* __restrict__ out0)
{
    const int bid = blockIdx.x;
    const int tid = threadIdx.x;
    if (bid < 2048) {
        const int i    = bid * 256 + tid;
        const int lane = i & 63;
        const int m    = lane & 15;
        const int kg   = lane >> 4;
        const int dc   = (i >> 6) & 7;
        const int kvb  = (i >> 9) & 63;
        const int b    = i >> 15;
        const float* s = K + ((size_t)(b * NSKV + kvb * 16 + m)) * ND + dc * 32 + kg * 8;
        float4 a = *(const float4*)s;
        float4 c = *(const float4*)(s + 4);
        bf16x8 o;
        o[0] = (__bf16)a.x; o[1] = (__bf16)a.y; o[2] = (__bf16)a.z; o[3] = (__bf16)a.w;
        o[4] = (__bf16)c.x; o[5] = (__bf16)c.y; o[6] = (__bf16)c.z; o[7] = (__bf16)c.w;
        ((bf16x8*)Kbf)[i] = o;
    } else if (bid < 2048 + 4096) {
        // mask -> bits: mw[row*64 + h*16 + m], bit c = mask[row][h*256+c*16+m]!=0
        const int row = (bid - 2048) * 4 + (tid >> 6);
        const int l   = tid & 63;
        const int4* mrow = (const int4*)(mask + (size_t)row * NSKV) + l * 4;
        unsigned w = 0;
        #pragma unroll
        for (int v = 0; v < 4; ++v) {
            int4 mv = mrow[v];
            w |= (mv.x != 0 ? 1u : 0u) << (v * 4 + 0);
            w |= (mv.y != 0 ? 1u : 0u) << (v * 4 + 1);
            w |= (mv.z != 0 ? 1u : 0u) << (v * 4 + 2);
            w |= (mv.w != 0 ? 1u : 0u) << (v * 4 + 3);
        }
        const int m    = l & 15;
        const int base = l & 48;
        unsigned out = 0;
        #pragma unroll
        for (int c = 0; c < 16; ++c) {
            unsigned v = (unsigned)__shfl((int)w, base | c);
            out |= ((v >> m) & 1u) << c;
        }
        mw[(size_t)row * 64 + l] = out;
    } else if (bid < 2048 + 4096 + 64) {
        colsum[(bid - 6144) * 256 + tid] = 0.f;
    } else {
        out0[(bid - 6208) * 256 + tid] = 0.f;
    }
}

// ---- main fused kernel (single pass, asm-pinned register double buffer) ----
// grid 1024 x 256 thr (4 waves); wave h owns k-quarter [h*256,+256).
// XCD swizzle keeps the K stream L2-resident (R3/R4: FETCH 43->27 MB).
// K fragments are loaded with inline-asm global_load_dwordx4 into fA/fB:
// an asm def cannot be sunk into its use by regalloc, so BOTH chunk buffers
// stay live (R1/R3/R4 collapse: VGPR 56-64 => serial L2 latency per chunk).
// The matching s_waitcnt is an asm with the fragments as "+v" tied operands:
// the MFMAs data-depend on it, so they cannot hoist above the wait (rule 18)
// and the values are pinned through the wait point.  Steady state: 16 loads
// (2 chunks) in flight per wave, 12 waves/CU (launch_bounds 256,3).
// Success signature: VGPR >= ~140.
__global__ __launch_bounds__(256, 3) void attn_fused(
    const float* __restrict__ Q, const __bf16* __restrict__ Kbf,
    const unsigned* __restrict__ mw, float* __restrict__ out_p,
    float* __restrict__ colsum)
{
    const int g    = blockIdx.x;
    const int tile = ((g & 7) << 7) | (g >> 3);   // bijective XCD swizzle
    const int b    = tile >> 6;
    const int q0   = (tile & 63) * 16;
    const int tid  = threadIdx.x;
    const int lane = tid & 63;
    const int h    = tid >> 6;       // wave id = k-quarter
    const int m    = lane & 15;      // MFMA A-row / B-col / C-col
    const int kg   = lane >> 4;      // quad: d-slice for A/B, row-group for C

    __shared__ __attribute__((aligned(16))) _Float16 epark[4][16 * EST]; // 34.3 KB
    __shared__ float Zs[4][16];
    __shared__ float invZs[16];

    _Float16* myE = &epark[h][0];

    // ---- A fragments: the block's 16 Q rows, f32 -> bf16 once ----
    bf16x8 afrag[8];
    {
        const float* qbase = Q + ((size_t)(b * NSQ + q0 + m)) * ND;
        #pragma unroll
        for (int dc = 0; dc < 8; ++dc) {
            const float* p4 = qbase + dc * 32 + kg * 8;
            float4 x = *(const float4*)(p4);
            float4 y = *(const float4*)(p4 + 4);
            bf16x8 a;
            a[0] = (__bf16)x.x; a[1] = (__bf16)x.y; a[2] = (__bf16)x.z; a[3] = (__bf16)x.w;
            a[4] = (__bf16)y.x; a[5] = (__bf16)y.y; a[6] = (__bf16)y.z; a[7] = (__bf16)y.w;
            afrag[dc] = a;
        }
    }

    unsigned mword[4];
    #pragma unroll
    for (int i = 0; i < 4; ++i)
        mword[i] = mw[(size_t)(b * NSQ + q0 + kg * 4 + i) * 64 + h * 16 + m];

    // per-lane byte base of this wave's kv-quarter fragment stream
    const char* kbase = (const char*)Kbf
                      + (size_t)(b * 64 + h * 16) * 8192 + lane * 16;

    float zacc[4] = {0.f, 0.f, 0.f, 0.f};
    bf16x8 fA[8], fB[8];

    // 8 x 16B loads for chunk c; offsets 0..3072 from two bases (13-bit imm limit)
    #define LDFRAG_ASM(gr, c) { \
        const char* _p0 = kbase + (size_t)(c) * 8192; \
        const char* _p1 = _p0 + 4096; \
        asm volatile( \
            "global_load_dwordx4 %0, %8, off\n\t" \
            "global_load_dwordx4 %1, %8, off offset:1024\n\t" \
            "global_load_dwordx4 %2, %8, off offset:2048\n\t" \
            "global_load_dwordx4 %3, %8, off offset:3072\n\t" \
            "global_load_dwordx4 %4, %9, off\n\t" \
            "global_load_dwordx4 %5, %9, off offset:1024\n\t" \
            "global_load_dwordx4 %6, %9, off offset:2048\n\t" \
            "global_load_dwordx4 %7, %9, off offset:3072" \
            : "=&v"((gr)[0]), "=&v"((gr)[1]), "=&v"((gr)[2]), "=&v"((gr)[3]), \
              "=&v"((gr)[4]), "=&v"((gr)[5]), "=&v"((gr)[6]), "=&v"((gr)[7]) \
            : "v"(_p0), "v"(_p1) \
            : "memory"); }

    // wait with the fragments as tied operands: pins values through the wait,
    // and makes consuming MFMAs data-depend on the waitcnt (no hoist).
    #define WAITPIN8(gr) { \
        asm volatile("s_waitcnt vmcnt(8)" \
            : "+v"((gr)[0]), "+v"((gr)[1]), "+v"((gr)[2]), "+v"((gr)[3]), \
              "+v"((gr)[4]), "+v"((gr)[5]), "+v"((gr)[6]), "+v"((gr)[7]) \
            :: "memory"); \
        __builtin_amdgcn_sched_barrier(0); }

    #define WAITPIN0(gr) { \
        asm volatile("s_waitcnt vmcnt(0)" \
            : "+v"((gr)[0]), "+v"((gr)[1]), "+v"((gr)[2]), "+v"((gr)[3]), \
              "+v"((gr)[4]), "+v"((gr)[5]), "+v"((gr)[6]), "+v"((gr)[7]) \
            :: "memory"); \
        __builtin_amdgcn_sched_barrier(0); }

    #define COMPUTE(gr, c) { \
        f32x4 acc = {0.f, 0.f, 0.f, 0.f}; \
        _Pragma("unroll") \
        for (int dc = 0; dc < 8; ++dc) \
            acc = __builtin_amdgcn_mfma_f32_16x16x32_bf16(afrag[dc], (gr)[dc], acc, 0, 0, 0); \
        _Pragma("unroll") \
        for (int i = 0; i < 4; ++i) { \
            float e = ((mword[i] >> (c)) & 1u) ? __expf(__expf(acc[i]) * 0.0625f) : 0.f; \
            zacc[i] += e; \
            myE[(kg * 4 + i) * EST + (c) * 16 + m] = (_Float16)e; \
        } }

    // prologue: chunks 0 and 1 in flight (16 outstanding)
    LDFRAG_ASM(fA, 0);
    LDFRAG_ASM(fB, 1);

    #pragma unroll
    for (int cc = 0; cc < 16; cc += 2) {
        WAITPIN8(fA);                           // fA(cc) landed; fB(cc+1) in flight
        COMPUTE(fA, cc);
        if (cc + 2 < 16) LDFRAG_ASM(fA, cc + 2);
        if (cc + 2 < 16) { WAITPIN8(fB); } else { WAITPIN0(fB); }
        COMPUTE(fB, cc + 1);
        if (cc + 3 < 16) LDFRAG_ASM(fB, cc + 3);
    }
    #undef LDFRAG_ASM
    #undef WAITPIN8
    #undef WAITPIN0
    #undef COMPUTE

    // ---- Z: reduce over 16 m-lanes, publish per-wave partials ----
    #pragma unroll
    for (int i = 0; i < 4; ++i) {
        float z = zacc[i];
        z += __shfl_xor(z, 1);
        z += __shfl_xor(z, 2);
        z += __shfl_xor(z, 4);
        z += __shfl_xor(z, 8);
        if (m == 0) Zs[h][kg * 4 + i] = z;
    }
    __syncthreads();
    if (tid < 16)
        invZs[tid] = 1.0f / (Zs[0][tid] + Zs[1][tid] + Zs[2][tid] + Zs[3][tid]);
    __syncthreads();

    // ---- write phase: full 1KB contiguous stores; colsum in-pass ----
    float csum[4] = {0.f, 0.f, 0.f, 0.f};
    float* prow = out_p + (size_t)(b * NSQ + q0) * NSKV + h * 256 + lane * 4;
    #pragma unroll
    for (int s = 0; s < 16; ++s) {
        f16x4 ev = *(const f16x4*)&myE[s * EST + lane * 4];
        const float iz = invZs[s];
        float4 pv;
        pv.x = (float)ev[0] * iz; pv.y = (float)ev[1] * iz;
        pv.z = (float)ev[2] * iz; pv.w = (float)ev[3] * iz;
        *(float4*)(prow + (size_t)s * NSKV) = pv;
        csum[0] += pv.x; csum[1] += pv.y; csum[2] += pv.z; csum[3] += pv.w;
    }
    #pragma unroll
    for (int j = 0; j < 4; ++j)
        atomicAdd(&colsum[b * NSKV + h * 256 + lane * 4 + j], csum[j]);
}

// out[b,d] = sum_k colsum[b,k] * V[b,k,d]; 1024 blocks, 16 k-rows each.
__global__ __launch_bounds__(256) void attn_out_kernel(
    const float* __restrict__ colsum, const float* __restrict__ V,
    float* __restrict__ out)
{
    const int b  = blockIdx.x >> 6;
    const int ks = (blockIdx.x & 63) << 4;
    const int d  = threadIdx.x;
    float acc = 0.f;
    #pragma unroll
    for (int k = 0; k < 16; ++k) {
        acc += colsum[b * NSKV + ks + k] * V[((size_t)(b * NSKV + ks + k)) * ND + d];
    }
    atomicAdd(&out[b * ND + d], acc);
}

extern "C" void kernel_launch(void* const* d_in, const int* in_sizes, int n_in,
                              void* d_out, int out_size, void* d_ws, size_t ws_size,
                              hipStream_t stream)
{
    (void)in_sizes; (void)n_in; (void)out_size; (void)ws_size;
    const float* Q    = (const float*)d_in[0];
    const float* K    = (const float*)d_in[1];
    const float* V    = (const float*)d_in[2];
    const int*   mask = (const int*)d_in[3];

    float* out0 = (float*)d_out;            // (B, D) = 4096 floats
    float* p    = out0 + NB * ND;           // p_attn (B, SQ, SKV)

    float*    colsum = (float*)d_ws;                                    // 64 KB
    __bf16*   Kbf    = (__bf16*)((char*)d_ws + (64 << 10));             // 8.39 MB
    unsigned* mwbits = (unsigned*)((char*)d_ws + (64 << 10) + (size_t)NB * NSKV * ND * 2); // 4.19 MB

    prep_kernel<<<6224, 256, 0, stream>>>(K, Kbf, mask, mwbits, colsum, out0);
    attn_fused<<<NB * 64, 256, 0, stream>>>(Q, Kbf, mwbits, p, colsum);
    attn_out_kernel<<<NB * 64, 256, 0, stream>>>(colsum, V, out0);
}

// Round 9
// 194.599 us; speedup vs baseline: 1.0915x; 1.0225x over previous
//
#include <hip/hip_runtime.h>

#define NB   16
#define NSQ  1024
#define NSKV 1024
#define ND   256

typedef float     f32x4  __attribute__((ext_vector_type(4)));
typedef _Float16  f16x4  __attribute__((ext_vector_type(4)));
typedef int       i32x4  __attribute__((ext_vector_type(4)));
typedef long      lng2   __attribute__((ext_vector_type(2)));

#define EST 268   // e-park LDS row stride in f16 elems (536 B): kg groups on disjoint banks

// HI must be an immediate for the builtin -> template parameter.
template<bool HI>
__device__ __forceinline__ int pk_fp8(float a, float b, int old) {
    return __builtin_amdgcn_cvt_pk_fp8_f32(a, b, old, HI);
}

// ---- merged prep: cvt K->fp8 e4m3 in MFMA-FRAGMENT ORDER | pack mask bits | zero colsum | zero out0
// Kb8 layout (8-byte fragment units, dc-pairs interleaved for 16B loads):
//   byte addr = ((b*64 + kvb)*4 + (dc>>1))*1024 + (kg*16+m)*16 + (dc&1)*8
// holding K[b][kvb*16 + m][dc*32 + kg*8 .. +8] as 8 e4m3 bytes (byte j = elem j).
// A 16B load at (chunk*4096 + j*1024 + lane*16) yields dc=2j (lo 8B) and dc=2j+1 (hi 8B).
__global__ __launch_bounds__(256) void prep_kernel(
    const float* __restrict__ K, unsigned char* __restrict__ Kb8,
    const int* __restrict__ mask, unsigned* __restrict__ mw,
    float* __restrict__ colsum, float* __restrict__ out0)
{
    const int bid = blockIdx.x;
    const int tid = threadIdx.x;
    if (bid < 2048) {
        const int i    = bid * 256 + tid;        // 8-elem group id
        const int lane = i & 63;
        const int m    = lane & 15;
        const int kg   = lane >> 4;
        const int dc   = (i >> 6) & 7;
        const int kvb  = (i >> 9) & 63;
        const int b    = i >> 15;
        const float* s = K + ((size_t)(b * NSKV + kvb * 16 + m)) * ND + dc * 32 + kg * 8;
        float4 a = *(const float4*)s;
        float4 c = *(const float4*)(s + 4);
        int lo = pk_fp8<false>(a.x, a.y, 0);
        lo     = pk_fp8<true >(a.z, a.w, lo);
        int hi = pk_fp8<false>(c.x, c.y, 0);
        hi     = pk_fp8<true >(c.z, c.w, hi);
        int2 w; w.x = lo; w.y = hi;
        const size_t obyte = ((size_t)((b * 64 + kvb) * 4 + (dc >> 1))) * 1024
                           + lane * 16 + (dc & 1) * 8;
        *(int2*)(Kb8 + obyte) = w;
    } else if (bid < 2048 + 4096) {
        // mask -> bits: mw[row*64 + h*16 + m], bit c = mask[row][h*256+c*16+m]!=0
        const int row = (bid - 2048) * 4 + (tid >> 6);
        const int l   = tid & 63;
        const int4* mrow = (const int4*)(mask + (size_t)row * NSKV) + l * 4;
        unsigned w = 0;
        #pragma unroll
        for (int v = 0; v < 4; ++v) {
            int4 mv = mrow[v];
            w |= (mv.x != 0 ? 1u : 0u) << (v * 4 + 0);
            w |= (mv.y != 0 ? 1u : 0u) << (v * 4 + 1);
            w |= (mv.z != 0 ? 1u : 0u) << (v * 4 + 2);
            w |= (mv.w != 0 ? 1u : 0u) << (v * 4 + 3);
        }
        const int m    = l & 15;
        const int base = l & 48;
        unsigned out = 0;
        #pragma unroll
        for (int c = 0; c < 16; ++c) {
            unsigned v = (unsigned)__shfl((int)w, base | c);
            out |= ((v >> m) & 1u) << c;
        }
        mw[(size_t)row * 64 + l] = out;
    } else if (bid < 2048 + 4096 + 64) {
        colsum[(bid - 6144) * 256 + tid] = 0.f;
    } else {
        out0[(bid - 6208) * 256 + tid] = 0.f;
    }
}

// ---- main fused kernel (R6 structure, fp8 operands) ----
// grid 1024 x 256 thr (4 waves); wave h owns k-quarter [h*256,+256).
// XCD swizzle keeps K L2-resident (R6: FETCH 14.8 MB).  Inline-asm
// global_load_dwordx4 double buffer (R6: cannot be collapsed by regalloc).
// R8 change: Q/K in OCP e4m3 -> 4 KB/chunk, 64 load-slots/wave (was 128),
// L2 read traffic 1 MB/CU (was 2), afrag/fA/fB register cost halved.
// mfma_f32_16x16x32_fp8_fp8, same MFMA count, same C layout.
// Loop form and wait placement identical to the PASSING R6 kernel.
__global__ __launch_bounds__(256, 4) void attn_fused(
    const float* __restrict__ Q, const unsigned char* __restrict__ Kb8,
    const unsigned* __restrict__ mw, float* __restrict__ out_p,
    float* __restrict__ colsum)
{
    const int g    = blockIdx.x;
    const int tile = ((g & 7) << 7) | (g >> 3);   // bijective XCD swizzle
    const int b    = tile >> 6;
    const int q0   = (tile & 63) * 16;
    const int tid  = threadIdx.x;
    const int lane = tid & 63;
    const int h    = tid >> 6;       // wave id = k-quarter
    const int m    = lane & 15;      // MFMA A-row / B-col / C-col
    const int kg   = lane >> 4;      // quad: d-slice for A/B, row-group for C

    __shared__ __attribute__((aligned(16))) _Float16 epark[4][16 * EST]; // 34.3 KB
    __shared__ float Zs[4][16];
    __shared__ float invZs[16];

    _Float16* myE = &epark[h][0];

    // ---- A fragments: 16 Q rows, f32 -> fp8 e4m3 once; 8B per dc ----
    long afrag[8];
    {
        const float* qbase = Q + ((size_t)(b * NSQ + q0 + m)) * ND;
        #pragma unroll
        for (int dc = 0; dc < 8; ++dc) {
            const float* p4 = qbase + dc * 32 + kg * 8;
            float4 x = *(const float4*)(p4);
            float4 y = *(const float4*)(p4 + 4);
            int lo = pk_fp8<false>(x.x, x.y, 0);
            lo     = pk_fp8<true >(x.z, x.w, lo);
            int hi = pk_fp8<false>(y.x, y.y, 0);
            hi     = pk_fp8<true >(y.z, y.w, hi);
            afrag[dc] = (long)(((unsigned long long)(unsigned)hi << 32) | (unsigned)lo);
        }
    }

    unsigned mword[4];
    #pragma unroll
    for (int i = 0; i < 4; ++i)
        mword[i] = mw[(size_t)(b * NSQ + q0 + kg * 4 + i) * 64 + h * 16 + m];

    // per-lane byte base of this wave's kv-quarter fp8 fragment stream
    const char* kbase = (const char*)Kb8
                      + (size_t)(b * 64 + h * 16) * 4096 + lane * 16;

    float zacc[4] = {0.f, 0.f, 0.f, 0.f};
    i32x4 fA[4], fB[4];

    // 4 x 16B loads for chunk c (4 KB total across the wave)
    #define LD4(gr, c) { \
        const char* _p0 = kbase + (size_t)(c) * 4096; \
        asm volatile( \
            "global_load_dwordx4 %0, %4, off\n\t" \
            "global_load_dwordx4 %1, %4, off offset:1024\n\t" \
            "global_load_dwordx4 %2, %4, off offset:2048\n\t" \
            "global_load_dwordx4 %3, %4, off offset:3072" \
            : "=&v"((gr)[0]), "=&v"((gr)[1]), "=&v"((gr)[2]), "=&v"((gr)[3]) \
            : "v"(_p0) \
            : "memory"); }

    // waits with fragments as tied operands: values pinned through the wait,
    // consuming MFMAs data-depend on the waitcnt (no hoist; rule 18).
    #define W4(gr) { \
        asm volatile("s_waitcnt vmcnt(4)" \
            : "+v"((gr)[0]), "+v"((gr)[1]), "+v"((gr)[2]), "+v"((gr)[3]) \
            :: "memory"); \
        __builtin_amdgcn_sched_barrier(0); }

    #define W0(gr) { \
        asm volatile("s_waitcnt vmcnt(0)" \
            : "+v"((gr)[0]), "+v"((gr)[1]), "+v"((gr)[2]), "+v"((gr)[3]) \
            :: "memory"); \
        __builtin_amdgcn_sched_barrier(0); }

    #define COMPUTE(gr, c) { \
        f32x4 acc = {0.f, 0.f, 0.f, 0.f}; \
        _Pragma("unroll") \
        for (int j = 0; j < 4; ++j) { \
            lng2 p_ = __builtin_bit_cast(lng2, (gr)[j]); \
            acc = __builtin_amdgcn_mfma_f32_16x16x32_fp8_fp8(afrag[2*j],   p_[0], acc, 0, 0, 0); \
            acc = __builtin_amdgcn_mfma_f32_16x16x32_fp8_fp8(afrag[2*j+1], p_[1], acc, 0, 0, 0); \
        } \
        _Pragma("unroll") \
        for (int i = 0; i < 4; ++i) { \
            float e = ((mword[i] >> (c)) & 1u) ? __expf(__expf(acc[i]) * 0.0625f) : 0.f; \
            zacc[i] += e; \
            myE[(kg * 4 + i) * EST + (c) * 16 + m] = (_Float16)e; \
        } }

    // prologue: chunks 0 and 1 in flight (8 outstanding)
    LD4(fA, 0);
    LD4(fB, 1);

    #pragma unroll
    for (int cc = 0; cc < 16; cc += 2) {
        W4(fA);                                 // fA(cc) landed; fB(cc+1) in flight
        COMPUTE(fA, cc);
        if (cc + 2 < 16) LD4(fA, cc + 2);
        if (cc + 2 < 16) { W4(fB); } else { W0(fB); }
        COMPUTE(fB, cc + 1);
        if (cc + 3 < 16) LD4(fB, cc + 3);
    }
    #undef LD4
    #undef W4
    #undef W0
    #undef COMPUTE

    // ---- Z: reduce over 16 m-lanes, publish per-wave partials ----
    #pragma unroll
    for (int i = 0; i < 4; ++i) {
        float z = zacc[i];
        z += __shfl_xor(z, 1);
        z += __shfl_xor(z, 2);
        z += __shfl_xor(z, 4);
        z += __shfl_xor(z, 8);
        if (m == 0) Zs[h][kg * 4 + i] = z;
    }
    __syncthreads();
    if (tid < 16)
        invZs[tid] = 1.0f / (Zs[0][tid] + Zs[1][tid] + Zs[2][tid] + Zs[3][tid]);
    __syncthreads();

    // ---- write phase: full 1KB contiguous stores; colsum in-pass ----
    float csum[4] = {0.f, 0.f, 0.f, 0.f};
    float* prow = out_p + (size_t)(b * NSQ + q0) * NSKV + h * 256 + lane * 4;
    #pragma unroll
    for (int s = 0; s < 16; ++s) {
        f16x4 ev = *(const f16x4*)&myE[s * EST + lane * 4];
        const float iz = invZs[s];
        float4 pv;
        pv.x = (float)ev[0] * iz; pv.y = (float)ev[1] * iz;
        pv.z = (float)ev[2] * iz; pv.w = (float)ev[3] * iz;
        *(float4*)(prow + (size_t)s * NSKV) = pv;
        csum[0] += pv.x; csum[1] += pv.y; csum[2] += pv.z; csum[3] += pv.w;
    }
    #pragma unroll
    for (int j = 0; j < 4; ++j)
        atomicAdd(&colsum[b * NSKV + h * 256 + lane * 4 + j], csum[j]);
}

// out[b,d] = sum_k colsum[b,k] * V[b,k,d]; 1024 blocks, 16 k-rows each.
__global__ __launch_bounds__(256) void attn_out_kernel(
    const float* __restrict__ colsum, const float* __restrict__ V,
    float* __restrict__ out)
{
    const int b  = blockIdx.x >> 6;
    const int ks = (blockIdx.x & 63) << 4;
    const int d  = threadIdx.x;
    float acc = 0.f;
    #pragma unroll
    for (int k = 0; k < 16; ++k) {
        acc += colsum[b * NSKV + ks + k] * V[((size_t)(b * NSKV + ks + k)) * ND + d];
    }
    atomicAdd(&out[b * ND + d], acc);
}

extern "C" void kernel_launch(void* const* d_in, const int* in_sizes, int n_in,
                              void* d_out, int out_size, void* d_ws, size_t ws_size,
                              hipStream_t stream)
{
    (void)in_sizes; (void)n_in; (void)out_size; (void)ws_size;
    const float* Q    = (const float*)d_in[0];
    const float* K    = (const float*)d_in[1];
    const float* V    = (const float*)d_in[2];
    const int*   mask = (const int*)d_in[3];

    float* out0 = (float*)d_out;            // (B, D) = 4096 floats
    float* p    = out0 + NB * ND;           // p_attn (B, SQ, SKV)

    float*         colsum = (float*)d_ws;                                   // 64 KB
    unsigned char* Kb8    = (unsigned char*)d_ws + (64 << 10);              // 4.19 MB fp8 frags
    unsigned*      mwbits = (unsigned*)((char*)d_ws + (64 << 10) + (size_t)NB * NSKV * ND); // 4.19 MB

    prep_kernel<<<6224, 256, 0, stream>>>(K, Kb8, mask, mwbits, colsum, out0);
    attn_fused<<<NB * 64, 256, 0, stream>>>(Q, Kb8, mwbits, p, colsum);
    attn_out_kernel<<<NB * 64, 256, 0, stream>>>(colsum, V, out0);
}

// Round 10
// 186.586 us; speedup vs baseline: 1.1384x; 1.0429x over previous
//
#include <hip/hip_runtime.h>

#define NB   16
#define NSQ  1024
#define NSKV 1024
#define ND   256

typedef float     f32x4  __attribute__((ext_vector_type(4)));
typedef _Float16  f16x4  __attribute__((ext_vector_type(4)));
typedef int       i32x4  __attribute__((ext_vector_type(4)));
typedef long      lng2   __attribute__((ext_vector_type(2)));

#define EST 268   // e-park LDS row stride in f16 elems (536 B): kg groups on disjoint banks

// HI must be an immediate for the builtin -> template parameter.
template<bool HI>
__device__ __forceinline__ int pk_fp8(float a, float b, int old) {
    return __builtin_amdgcn_cvt_pk_fp8_f32(a, b, old, HI);
}

// ---- merged prep: cvt K->fp8 e4m3 in MFMA-FRAGMENT ORDER | pack mask bits | zero colsum | zero out0
// Kb8 layout (8-byte fragment units, dc-pairs interleaved for 16B loads):
//   byte addr = ((b*64 + kvb)*4 + (dc>>1))*1024 + (kg*16+m)*16 + (dc&1)*8
// holding K[b][kvb*16 + m][dc*32 + kg*8 .. +8] as 8 e4m3 bytes (byte j = elem j).
__global__ __launch_bounds__(256) void prep_kernel(
    const float* __restrict__ K, unsigned char* __restrict__ Kb8,
    const int* __restrict__ mask, unsigned* __restrict__ mw,
    float* __restrict__ colsum, float* __restrict__ out0)
{
    const int bid = blockIdx.x;
    const int tid = threadIdx.x;
    if (bid < 2048) {
        const int i    = bid * 256 + tid;        // 8-elem group id
        const int lane = i & 63;
        const int m    = lane & 15;
        const int kg   = lane >> 4;
        const int dc   = (i >> 6) & 7;
        const int kvb  = (i >> 9) & 63;
        const int b    = i >> 15;
        const float* s = K + ((size_t)(b * NSKV + kvb * 16 + m)) * ND + dc * 32 + kg * 8;
        float4 a = *(const float4*)s;
        float4 c = *(const float4*)(s + 4);
        int lo = pk_fp8<false>(a.x, a.y, 0);
        lo     = pk_fp8<true >(a.z, a.w, lo);
        int hi = pk_fp8<false>(c.x, c.y, 0);
        hi     = pk_fp8<true >(c.z, c.w, hi);
        int2 w; w.x = lo; w.y = hi;
        const size_t obyte = ((size_t)((b * 64 + kvb) * 4 + (dc >> 1))) * 1024
                           + lane * 16 + (dc & 1) * 8;
        *(int2*)(Kb8 + obyte) = w;
    } else if (bid < 2048 + 4096) {
        // mask -> bits: mw[row*64 + h*16 + m], bit c = mask[row][h*256+c*16+m]!=0
        const int row = (bid - 2048) * 4 + (tid >> 6);
        const int l   = tid & 63;
        const int4* mrow = (const int4*)(mask + (size_t)row * NSKV) + l * 4;
        unsigned w = 0;
        #pragma unroll
        for (int v = 0; v < 4; ++v) {
            int4 mv = mrow[v];
            w |= (mv.x != 0 ? 1u : 0u) << (v * 4 + 0);
            w |= (mv.y != 0 ? 1u : 0u) << (v * 4 + 1);
            w |= (mv.z != 0 ? 1u : 0u) << (v * 4 + 2);
            w |= (mv.w != 0 ? 1u : 0u) << (v * 4 + 3);
        }
        const int m    = l & 15;
        const int base = l & 48;
        unsigned out = 0;
        #pragma unroll
        for (int c = 0; c < 16; ++c) {
            unsigned v = (unsigned)__shfl((int)w, base | c);
            out |= ((v >> m) & 1u) << c;
        }
        mw[(size_t)row * 64 + l] = out;
    } else if (bid < 2048 + 4096 + 64) {
        colsum[(bid - 6144) * 256 + tid] = 0.f;
    } else {
        out0[(bid - 6208) * 256 + tid] = 0.f;
    }
}

// ---- main fused kernel (R9 loop skeleton, 2 q-subtiles per wave) ----
// grid 512 x 256 thr (4 waves); wave h owns k-quarter [h*256,+256); each wave
// computes TWO 16-row q-subtiles (rows q0..q0+15 and q0+16..q0+31).
// Why: R9 proved the wall is not the K stream (fp8 halved loads, -4%).  The
// remaining per-wave cost is the 16-deep dependent MFMA chain per chunk
// (in-order issue, no within-wave ILP).  Two independent acc chains
// interleaved in program order fill the dependency bubbles; loads amortize
// 2x; wave count halves; L2 traffic halves.
// Loop form, asm load/wait macros identical to the PASSING R9 kernel.
__global__ __launch_bounds__(256, 2) void attn_fused(
    const float* __restrict__ Q, const unsigned char* __restrict__ Kb8,
    const unsigned* __restrict__ mw, float* __restrict__ out_p,
    float* __restrict__ colsum)
{
    const int g    = blockIdx.x;
    const int tile = ((g & 7) << 6) | (g >> 3);   // bijective XCD swizzle (512)
    const int b    = tile >> 5;
    const int q0   = (tile & 31) * 32;
    const int tid  = threadIdx.x;
    const int lane = tid & 63;
    const int h    = tid >> 6;       // wave id = k-quarter
    const int m    = lane & 15;      // MFMA A-row / B-col / C-col
    const int kg   = lane >> 4;      // quad: d-slice for A/B, row-group for C

    __shared__ __attribute__((aligned(16))) _Float16 epark[2][4][16 * EST]; // 68.6 KB
    __shared__ float Zs[2][4][16];
    __shared__ float invZs[2][16];

    _Float16* myE0 = &epark[0][h][0];
    _Float16* myE1 = &epark[1][h][0];

    // ---- A fragments: 2 x 16 Q rows, f32 -> fp8 e4m3 once ----
    long afragA[8], afragB[8];
    #pragma unroll
    for (int sub = 0; sub < 2; ++sub) {
        const float* qbase = Q + ((size_t)(b * NSQ + q0 + sub * 16 + m)) * ND;
        #pragma unroll
        for (int dc = 0; dc < 8; ++dc) {
            const float* p4 = qbase + dc * 32 + kg * 8;
            float4 x = *(const float4*)(p4);
            float4 y = *(const float4*)(p4 + 4);
            int lo = pk_fp8<false>(x.x, x.y, 0);
            lo     = pk_fp8<true >(x.z, x.w, lo);
            int hi = pk_fp8<false>(y.x, y.y, 0);
            hi     = pk_fp8<true >(y.z, y.w, hi);
            long v = (long)(((unsigned long long)(unsigned)hi << 32) | (unsigned)lo);
            if (sub == 0) afragA[dc] = v; else afragB[dc] = v;
        }
    }

    unsigned mwordA[4], mwordB[4];
    #pragma unroll
    for (int i = 0; i < 4; ++i) {
        mwordA[i] = mw[(size_t)(b * NSQ + q0 +      kg * 4 + i) * 64 + h * 16 + m];
        mwordB[i] = mw[(size_t)(b * NSQ + q0 + 16 + kg * 4 + i) * 64 + h * 16 + m];
    }

    // per-lane byte base of this wave's kv-quarter fp8 fragment stream
    const char* kbase = (const char*)Kb8
                      + (size_t)(b * 64 + h * 16) * 4096 + lane * 16;

    float zaccA[4] = {0.f, 0.f, 0.f, 0.f};
    float zaccB[4] = {0.f, 0.f, 0.f, 0.f};
    i32x4 fA[4], fB[4];

    // 4 x 16B loads for chunk c (4 KB total across the wave)
    #define LD4(gr, c) { \
        const char* _p0 = kbase + (size_t)(c) * 4096; \
        asm volatile( \
            "global_load_dwordx4 %0, %4, off\n\t" \
            "global_load_dwordx4 %1, %4, off offset:1024\n\t" \
            "global_load_dwordx4 %2, %4, off offset:2048\n\t" \
            "global_load_dwordx4 %3, %4, off offset:3072" \
            : "=&v"((gr)[0]), "=&v"((gr)[1]), "=&v"((gr)[2]), "=&v"((gr)[3]) \
            : "v"(_p0) \
            : "memory"); }

    #define W4(gr) { \
        asm volatile("s_waitcnt vmcnt(4)" \
            : "+v"((gr)[0]), "+v"((gr)[1]), "+v"((gr)[2]), "+v"((gr)[3]) \
            :: "memory"); \
        __builtin_amdgcn_sched_barrier(0); }

    #define W0(gr) { \
        asm volatile("s_waitcnt vmcnt(0)" \
            : "+v"((gr)[0]), "+v"((gr)[1]), "+v"((gr)[2]), "+v"((gr)[3]) \
            :: "memory"); \
        __builtin_amdgcn_sched_barrier(0); }

    // two independent acc chains, interleaved in program order (in-order
    // issue: chain B's MFMA fills chain A's dependent-latency bubble)
    #define COMPUTE(gr, c) { \
        f32x4 accA = {0.f, 0.f, 0.f, 0.f}; \
        f32x4 accB = {0.f, 0.f, 0.f, 0.f}; \
        _Pragma("unroll") \
        for (int j = 0; j < 4; ++j) { \
            lng2 p_ = __builtin_bit_cast(lng2, (gr)[j]); \
            accA = __builtin_amdgcn_mfma_f32_16x16x32_fp8_fp8(afragA[2*j],   p_[0], accA, 0, 0, 0); \
            accB = __builtin_amdgcn_mfma_f32_16x16x32_fp8_fp8(afragB[2*j],   p_[0], accB, 0, 0, 0); \
            accA = __builtin_amdgcn_mfma_f32_16x16x32_fp8_fp8(afragA[2*j+1], p_[1], accA, 0, 0, 0); \
            accB = __builtin_amdgcn_mfma_f32_16x16x32_fp8_fp8(afragB[2*j+1], p_[1], accB, 0, 0, 0); \
        } \
        _Pragma("unroll") \
        for (int i = 0; i < 4; ++i) { \
            float eA = ((mwordA[i] >> (c)) & 1u) ? __expf(__expf(accA[i]) * 0.0625f) : 0.f; \
            float eB = ((mwordB[i] >> (c)) & 1u) ? __expf(__expf(accB[i]) * 0.0625f) : 0.f; \
            zaccA[i] += eA; \
            zaccB[i] += eB; \
            myE0[(kg * 4 + i) * EST + (c) * 16 + m] = (_Float16)eA; \
            myE1[(kg * 4 + i) * EST + (c) * 16 + m] = (_Float16)eB; \
        } }

    // prologue: chunks 0 and 1 in flight (8 outstanding)
    LD4(fA, 0);
    LD4(fB, 1);

    #pragma unroll
    for (int cc = 0; cc < 16; cc += 2) {
        W4(fA);                                 // fA(cc) landed; fB(cc+1) in flight
        COMPUTE(fA, cc);
        if (cc + 2 < 16) LD4(fA, cc + 2);
        if (cc + 2 < 16) { W4(fB); } else { W0(fB); }
        COMPUTE(fB, cc + 1);
        if (cc + 3 < 16) LD4(fB, cc + 3);
    }
    #undef LD4
    #undef W4
    #undef W0
    #undef COMPUTE

    // ---- Z: reduce over 16 m-lanes, publish per-wave partials ----
    #pragma unroll
    for (int i = 0; i < 4; ++i) {
        float zA = zaccA[i];
        zA += __shfl_xor(zA, 1);
        zA += __shfl_xor(zA, 2);
        zA += __shfl_xor(zA, 4);
        zA += __shfl_xor(zA, 8);
        float zB = zaccB[i];
        zB += __shfl_xor(zB, 1);
        zB += __shfl_xor(zB, 2);
        zB += __shfl_xor(zB, 4);
        zB += __shfl_xor(zB, 8);
        if (m == 0) {
            Zs[0][h][kg * 4 + i] = zA;
            Zs[1][h][kg * 4 + i] = zB;
        }
    }
    __syncthreads();
    if (tid < 16)
        invZs[0][tid] = 1.0f / (Zs[0][0][tid] + Zs[0][1][tid] + Zs[0][2][tid] + Zs[0][3][tid]);
    else if (tid < 32)
        invZs[1][tid - 16] = 1.0f / (Zs[1][0][tid - 16] + Zs[1][1][tid - 16] + Zs[1][2][tid - 16] + Zs[1][3][tid - 16]);
    __syncthreads();

    // ---- write phase: full 1KB contiguous stores; colsum in-pass ----
    float csum[4] = {0.f, 0.f, 0.f, 0.f};
    float* prowA = out_p + (size_t)(b * NSQ + q0) * NSKV + h * 256 + lane * 4;
    #pragma unroll
    for (int s = 0; s < 16; ++s) {
        f16x4 ev = *(const f16x4*)&myE0[s * EST + lane * 4];
        const float iz = invZs[0][s];
        float4 pv;
        pv.x = (float)ev[0] * iz; pv.y = (float)ev[1] * iz;
        pv.z = (float)ev[2] * iz; pv.w = (float)ev[3] * iz;
        *(float4*)(prowA + (size_t)s * NSKV) = pv;
        csum[0] += pv.x; csum[1] += pv.y; csum[2] += pv.z; csum[3] += pv.w;
    }
    float* prowB = prowA + (size_t)16 * NSKV;
    #pragma unroll
    for (int s = 0; s < 16; ++s) {
        f16x4 ev = *(const f16x4*)&myE1[s * EST + lane * 4];
        const float iz = invZs[1][s];
        float4 pv;
        pv.x = (float)ev[0] * iz; pv.y = (float)ev[1] * iz;
        pv.z = (float)ev[2] * iz; pv.w = (float)ev[3] * iz;
        *(float4*)(prowB + (size_t)s * NSKV) = pv;
        csum[0] += pv.x; csum[1] += pv.y; csum[2] += pv.z; csum[3] += pv.w;
    }
    #pragma unroll
    for (int j = 0; j < 4; ++j)
        atomicAdd(&colsum[b * NSKV + h * 256 + lane * 4 + j], csum[j]);
}

// out[b,d] = sum_k colsum[b,k] * V[b,k,d]; 1024 blocks, 16 k-rows each.
__global__ __launch_bounds__(256) void attn_out_kernel(
    const float* __restrict__ colsum, const float* __restrict__ V,
    float* __restrict__ out)
{
    const int b  = blockIdx.x >> 6;
    const int ks = (blockIdx.x & 63) << 4;
    const int d  = threadIdx.x;
    float acc = 0.f;
    #pragma unroll
    for (int k = 0; k < 16; ++k) {
        acc += colsum[b * NSKV + ks + k] * V[((size_t)(b * NSKV + ks + k)) * ND + d];
    }
    atomicAdd(&out[b * ND + d], acc);
}

extern "C" void kernel_launch(void* const* d_in, const int* in_sizes, int n_in,
                              void* d_out, int out_size, void* d_ws, size_t ws_size,
                              hipStream_t stream)
{
    (void)in_sizes; (void)n_in; (void)out_size; (void)ws_size;
    const float* Q    = (const float*)d_in[0];
    const float* K    = (const float*)d_in[1];
    const float* V    = (const float*)d_in[2];
    const int*   mask = (const int*)d_in[3];

    float* out0 = (float*)d_out;            // (B, D) = 4096 floats
    float* p    = out0 + NB * ND;           // p_attn (B, SQ, SKV)

    float*         colsum = (float*)d_ws;                                   // 64 KB
    unsigned char* Kb8    = (unsigned char*)d_ws + (64 << 10);              // 4.19 MB fp8 frags
    unsigned*      mwbits = (unsigned*)((char*)d_ws + (64 << 10) + (size_t)NB * NSKV * ND); // 4.19 MB

    prep_kernel<<<6224, 256, 0, stream>>>(K, Kb8, mask, mwbits, colsum, out0);
    attn_fused<<<512, 256, 0, stream>>>(Q, Kb8, mwbits, p, colsum);
    attn_out_kernel<<<NB * 64, 256, 0, stream>>>(colsum, V, out0);
}

// Round 11
// 185.357 us; speedup vs baseline: 1.1459x; 1.0066x over previous
//
#include <hip/hip_runtime.h>

#define NB   16
#define NSQ  1024
#define NSKV 1024
#define ND   256

typedef float     f32x4  __attribute__((ext_vector_type(4)));
typedef _Float16  f16x4  __attribute__((ext_vector_type(4)));
typedef int       i32x4  __attribute__((ext_vector_type(4)));
typedef long      lng2   __attribute__((ext_vector_type(2)));

#define EST 268   // e-park LDS row stride in f16 elems (536 B): kg groups on disjoint banks

// HI must be an immediate for the builtin -> template parameter.
template<bool HI>
__device__ __forceinline__ int pk_fp8(float a, float b, int old) {
    return __builtin_amdgcn_cvt_pk_fp8_f32(a, b, old, HI);
}

// ---- merged prep: cvt K->fp8 e4m3 in MFMA-FRAGMENT ORDER | pack mask bits | zero out0
// Kb8 layout (8-byte fragment units, dc-pairs interleaved for 16B loads):
//   byte addr = ((b*64 + kvb)*4 + (dc>>1))*1024 + (kg*16+m)*16 + (dc&1)*8
// holding K[b][kvb*16 + m][dc*32 + kg*8 .. +8] as 8 e4m3 bytes (byte j = elem j).
// (colsum zeroing dropped: R11 uses fully-written partial stores instead of atomics.)
__global__ __launch_bounds__(256) void prep_kernel(
    const float* __restrict__ K, unsigned char* __restrict__ Kb8,
    const int* __restrict__ mask, unsigned* __restrict__ mw,
    float* __restrict__ out0)
{
    const int bid = blockIdx.x;
    const int tid = threadIdx.x;
    if (bid < 2048) {
        const int i    = bid * 256 + tid;        // 8-elem group id
        const int lane = i & 63;
        const int m    = lane & 15;
        const int kg   = lane >> 4;
        const int dc   = (i >> 6) & 7;
        const int kvb  = (i >> 9) & 63;
        const int b    = i >> 15;
        const float* s = K + ((size_t)(b * NSKV + kvb * 16 + m)) * ND + dc * 32 + kg * 8;
        float4 a = *(const float4*)s;
        float4 c = *(const float4*)(s + 4);
        int lo = pk_fp8<false>(a.x, a.y, 0);
        lo     = pk_fp8<true >(a.z, a.w, lo);
        int hi = pk_fp8<false>(c.x, c.y, 0);
        hi     = pk_fp8<true >(c.z, c.w, hi);
        int2 w; w.x = lo; w.y = hi;
        const size_t obyte = ((size_t)((b * 64 + kvb) * 4 + (dc >> 1))) * 1024
                           + lane * 16 + (dc & 1) * 8;
        *(int2*)(Kb8 + obyte) = w;
    } else if (bid < 2048 + 4096) {
        // mask -> bits: mw[row*64 + h*16 + m], bit c = mask[row][h*256+c*16+m]!=0
        const int row = (bid - 2048) * 4 + (tid >> 6);
        const int l   = tid & 63;
        const int4* mrow = (const int4*)(mask + (size_t)row * NSKV) + l * 4;
        unsigned w = 0;
        #pragma unroll
        for (int v = 0; v < 4; ++v) {
            int4 mv = mrow[v];
            w |= (mv.x != 0 ? 1u : 0u) << (v * 4 + 0);
            w |= (mv.y != 0 ? 1u : 0u) << (v * 4 + 1);
            w |= (mv.z != 0 ? 1u : 0u) << (v * 4 + 2);
            w |= (mv.w != 0 ? 1u : 0u) << (v * 4 + 3);
        }
        const int m    = l & 15;
        const int base = l & 48;
        unsigned out = 0;
        #pragma unroll
        for (int c = 0; c < 16; ++c) {
            unsigned v = (unsigned)__shfl((int)w, base | c);
            out |= ((v >> m) & 1u) << c;
        }
        mw[(size_t)row * 64 + l] = out;
    } else {
        out0[(bid - 6144) * 256 + tid] = 0.f;
    }
}

// ---- main fused kernel (R9 tile shape + R10's dual-chain ILP moved to the kv axis) ----
// grid 1024 x 256 thr (4 waves); block = 16 q-rows; wave h owns k-quarter
// [h*256,+256).  Chunks processed in PAIRS: two independent acc chains
// (chunk cc and cc+1) with interleaved MFMAs fill the dependent-latency
// bubbles (R10's proven mechanism), while the 16-row tile keeps LDS at
// 34.3 KB -> 4 blocks/CU = 16 waves/CU (2x R10's TLP).  4 register buffers,
// 16 loads in flight, vmcnt(8) pair waits; asm load/wait discipline from the
// passing R9/R10 kernels.  colsum: non-atomic per-tile partials (cs_part),
// reduced in attn_out -- removes ~1M contended atomics from the tail.
__global__ __launch_bounds__(256, 4) void attn_fused(
    const float* __restrict__ Q, const unsigned char* __restrict__ Kb8,
    const unsigned* __restrict__ mw, float* __restrict__ out_p,
    float* __restrict__ cs_part)
{
    const int g    = blockIdx.x;
    const int tile = ((g & 7) << 7) | (g >> 3);   // bijective XCD swizzle
    const int b    = tile >> 6;
    const int qt   = tile & 63;
    const int q0   = qt * 16;
    const int tid  = threadIdx.x;
    const int lane = tid & 63;
    const int h    = tid >> 6;       // wave id = k-quarter
    const int m    = lane & 15;      // MFMA A-row / B-col / C-col
    const int kg   = lane >> 4;      // quad: d-slice for A/B, row-group for C

    __shared__ __attribute__((aligned(16))) _Float16 epark[4][16 * EST]; // 34.3 KB
    __shared__ float Zs[4][16];
    __shared__ float invZs[16];

    _Float16* myE = &epark[h][0];

    // ---- A fragments: 16 Q rows, f32 -> fp8 e4m3 once; 8B per dc ----
    long afrag[8];
    {
        const float* qbase = Q + ((size_t)(b * NSQ + q0 + m)) * ND;
        #pragma unroll
        for (int dc = 0; dc < 8; ++dc) {
            const float* p4 = qbase + dc * 32 + kg * 8;
            float4 x = *(const float4*)(p4);
            float4 y = *(const float4*)(p4 + 4);
            int lo = pk_fp8<false>(x.x, x.y, 0);
            lo     = pk_fp8<true >(x.z, x.w, lo);
            int hi = pk_fp8<false>(y.x, y.y, 0);
            hi     = pk_fp8<true >(y.z, y.w, hi);
            afrag[dc] = (long)(((unsigned long long)(unsigned)hi << 32) | (unsigned)lo);
        }
    }

    unsigned mword[4];
    #pragma unroll
    for (int i = 0; i < 4; ++i)
        mword[i] = mw[(size_t)(b * NSQ + q0 + kg * 4 + i) * 64 + h * 16 + m];

    // per-lane byte base of this wave's kv-quarter fp8 fragment stream
    const char* kbase = (const char*)Kb8
                      + (size_t)(b * 64 + h * 16) * 4096 + lane * 16;

    float zacc[4] = {0.f, 0.f, 0.f, 0.f};
    i32x4 fA[4], fB[4], fC[4], fD[4];

    // 4 x 16B loads for chunk c (4 KB total across the wave)
    #define LD4(gr, c) { \
        const char* _p0 = kbase + (size_t)(c) * 4096; \
        asm volatile( \
            "global_load_dwordx4 %0, %4, off\n\t" \
            "global_load_dwordx4 %1, %4, off offset:1024\n\t" \
            "global_load_dwordx4 %2, %4, off offset:2048\n\t" \
            "global_load_dwordx4 %3, %4, off offset:3072" \
            : "=&v"((gr)[0]), "=&v"((gr)[1]), "=&v"((gr)[2]), "=&v"((gr)[3]) \
            : "v"(_p0) \
            : "memory"); }

    // pair waits: both buffers' values pinned through the wait; consuming
    // MFMAs data-depend on the waitcnt (no hoist; rule 18).
    #define W8P(g1, g2) { \
        asm volatile("s_waitcnt vmcnt(8)" \
            : "+v"((g1)[0]), "+v"((g1)[1]), "+v"((g1)[2]), "+v"((g1)[3]), \
              "+v"((g2)[0]), "+v"((g2)[1]), "+v"((g2)[2]), "+v"((g2)[3]) \
            :: "memory"); \
        __builtin_amdgcn_sched_barrier(0); }

    #define W0P(g1, g2) { \
        asm volatile("s_waitcnt vmcnt(0)" \
            : "+v"((g1)[0]), "+v"((g1)[1]), "+v"((g1)[2]), "+v"((g1)[3]), \
              "+v"((g2)[0]), "+v"((g2)[1]), "+v"((g2)[2]), "+v"((g2)[3]) \
            :: "memory"); \
        __builtin_amdgcn_sched_barrier(0); }

    // two chunks, two independent acc chains, MFMAs interleaved
    #define COMPUTE2(gE, gO, cE, cO) { \
        f32x4 accE = {0.f, 0.f, 0.f, 0.f}; \
        f32x4 accO = {0.f, 0.f, 0.f, 0.f}; \
        _Pragma("unroll") \
        for (int j = 0; j < 4; ++j) { \
            lng2 pE = __builtin_bit_cast(lng2, (gE)[j]); \
            lng2 pO = __builtin_bit_cast(lng2, (gO)[j]); \
            accE = __builtin_amdgcn_mfma_f32_16x16x32_fp8_fp8(afrag[2*j],   pE[0], accE, 0, 0, 0); \
            accO = __builtin_amdgcn_mfma_f32_16x16x32_fp8_fp8(afrag[2*j],   pO[0], accO, 0, 0, 0); \
            accE = __builtin_amdgcn_mfma_f32_16x16x32_fp8_fp8(afrag[2*j+1], pE[1], accE, 0, 0, 0); \
            accO = __builtin_amdgcn_mfma_f32_16x16x32_fp8_fp8(afrag[2*j+1], pO[1], accO, 0, 0, 0); \
        } \
        _Pragma("unroll") \
        for (int i = 0; i < 4; ++i) { \
            float eE = ((mword[i] >> (cE)) & 1u) ? __expf(__expf(accE[i]) * 0.0625f) : 0.f; \
            float eO = ((mword[i] >> (cO)) & 1u) ? __expf(__expf(accO[i]) * 0.0625f) : 0.f; \
            zacc[i] += eE; \
            zacc[i] += eO; \
            myE[(kg * 4 + i) * EST + (cE) * 16 + m] = (_Float16)eE; \
            myE[(kg * 4 + i) * EST + (cO) * 16 + m] = (_Float16)eO; \
        } }

    // prologue: chunks 0..3 in flight (16 outstanding)
    LD4(fA, 0);
    LD4(fB, 1);
    LD4(fC, 2);
    LD4(fD, 3);

    #pragma unroll
    for (int cc = 0; cc < 16; cc += 4) {
        W8P(fA, fB);                            // chunks cc,cc+1 landed
        COMPUTE2(fA, fB, cc, cc + 1);
        if (cc + 4 < 16) { LD4(fA, cc + 4); LD4(fB, cc + 5); }
        if (cc + 4 < 16) { W8P(fC, fD); } else { W0P(fC, fD); }
        COMPUTE2(fC, fD, cc + 2, cc + 3);
        if (cc + 4 < 16) { LD4(fC, cc + 6); LD4(fD, cc + 7); }
    }
    #undef LD4
    #undef W8P
    #undef W0P
    #undef COMPUTE2

    // ---- Z: reduce over 16 m-lanes, publish per-wave partials ----
    #pragma unroll
    for (int i = 0; i < 4; ++i) {
        float z = zacc[i];
        z += __shfl_xor(z, 1);
        z += __shfl_xor(z, 2);
        z += __shfl_xor(z, 4);
        z += __shfl_xor(z, 8);
        if (m == 0) Zs[h][kg * 4 + i] = z;
    }
    __syncthreads();
    if (tid < 16)
        invZs[tid] = 1.0f / (Zs[0][tid] + Zs[1][tid] + Zs[2][tid] + Zs[3][tid]);
    __syncthreads();

    // ---- write phase: full 1KB contiguous stores; csum -> non-atomic partials ----
    float csum[4] = {0.f, 0.f, 0.f, 0.f};
    float* prow = out_p + (size_t)(b * NSQ + q0) * NSKV + h * 256 + lane * 4;
    #pragma unroll
    for (int s = 0; s < 16; ++s) {
        f16x4 ev = *(const f16x4*)&myE[s * EST + lane * 4];
        const float iz = invZs[s];
        float4 pv;
        pv.x = (float)ev[0] * iz; pv.y = (float)ev[1] * iz;
        pv.z = (float)ev[2] * iz; pv.w = (float)ev[3] * iz;
        *(float4*)(prow + (size_t)s * NSKV) = pv;
        csum[0] += pv.x; csum[1] += pv.y; csum[2] += pv.z; csum[3] += pv.w;
    }
    // cs_part[(b*1024 + k)*64 + qt], k = h*256 + lane*4 + j
    #pragma unroll
    for (int j = 0; j < 4; ++j) {
        const int k = h * 256 + lane * 4 + j;
        cs_part[((size_t)(b * NSKV + k)) * 64 + qt] = csum[j];
    }
}

// out[b,d] = sum_k colsum[b,k] * V[b,k,d]; colsum reduced from 64 per-tile
// partials (4 KB contiguous float4 read per block).  1024 blocks, 16 k each.
__global__ __launch_bounds__(256) void attn_out_kernel(
    const float* __restrict__ cs_part, const float* __restrict__ V,
    float* __restrict__ out)
{
    const int b  = blockIdx.x >> 6;
    const int ks = (blockIdx.x & 63) << 4;
    const int tid = threadIdx.x;

    __shared__ float cs16[16];

    // reduce partials: 1024 floats = 16 k x 64 tiles, contiguous
    {
        const float* base = cs_part + ((size_t)(b * NSKV + ks)) * 64;
        float4 v = *(const float4*)(base + tid * 4);
        float s = v.x + v.y + v.z + v.w;
        s += __shfl_xor(s, 1);
        s += __shfl_xor(s, 2);
        s += __shfl_xor(s, 4);
        s += __shfl_xor(s, 8);
        if ((tid & 15) == 0) cs16[tid >> 4] = s;
    }
    __syncthreads();

    const int d = tid;
    float acc = 0.f;
    #pragma unroll
    for (int k = 0; k < 16; ++k) {
        acc += cs16[k] * V[((size_t)(b * NSKV + ks + k)) * ND + d];
    }
    atomicAdd(&out[b * ND + d], acc);
}

extern "C" void kernel_launch(void* const* d_in, const int* in_sizes, int n_in,
                              void* d_out, int out_size, void* d_ws, size_t ws_size,
                              hipStream_t stream)
{
    (void)in_sizes; (void)n_in; (void)out_size; (void)ws_size;
    const float* Q    = (const float*)d_in[0];
    const float* K    = (const float*)d_in[1];
    const float* V    = (const float*)d_in[2];
    const int*   mask = (const int*)d_in[3];

    float* out0 = (float*)d_out;            // (B, D) = 4096 floats
    float* p    = out0 + NB * ND;           // p_attn (B, SQ, SKV)

    float*         cs_part = (float*)d_ws;                                  // 4.19 MB partials
    unsigned char* Kb8     = (unsigned char*)d_ws + ((size_t)NB * NSKV * 64 * 4);       // 4.19 MB fp8 frags
    unsigned*      mwbits  = (unsigned*)((char*)Kb8 + (size_t)NB * NSKV * ND);          // 4.19 MB

    prep_kernel<<<6160, 256, 0, stream>>>(K, Kb8, mask, mwbits, out0);
    attn_fused<<<NB * 64, 256, 0, stream>>>(Q, Kb8, mwbits, p, cs_part);
    attn_out_kernel<<<NB * 64, 256, 0, stream>>>(cs_part, V, out0);
}